// Round 1
// baseline (1708.660 us; speedup 1.0000x reference)
//
#include <hip/hip_runtime.h>
#include <cmath>

// ---------- helpers ----------
static __device__ __forceinline__ unsigned encf(float f) {
    unsigned u = __float_as_uint(f);
    return (u & 0x80000000u) ? ~u : (u | 0x80000000u);
}
static __device__ __forceinline__ float decf(unsigned u) {
    return (u & 0x80000000u) ? __uint_as_float(u & 0x7fffffffu) : __uint_as_float(~u);
}
#define ENC_NEG_INF 0x007FFFFFu   // encf(-inf)

__global__ void fill_f32_k(float* __restrict__ p, size_t n, float v) {
    size_t i = (size_t)blockIdx.x * blockDim.x + threadIdx.x;
    if (i < n) p[i] = v;
}
__global__ void fill_u32_k(unsigned* __restrict__ p, size_t n, unsigned v) {
    size_t i = (size_t)blockIdx.x * blockDim.x + threadIdx.x;
    if (i < n) p[i] = v;
}

// ---------- GEMM: Y[N,NOUT] = X[N,K] @ W[K,NOUT], R rows per block ----------
template<int K, int NOUT, int R>
__global__ void gemm_rows_k(const float* __restrict__ X, const float* __restrict__ W,
                            float* __restrict__ Y, int N) {
    __shared__ float xs[R][K];
    int n0 = blockIdx.x * R;
    for (int i = threadIdx.x; i < R * K; i += blockDim.x) {
        int r = i / K, k = i % K;
        int n = n0 + r;
        xs[r][k] = (n < N) ? X[(size_t)n * K + k] : 0.f;
    }
    __syncthreads();
    for (int c = threadIdx.x; c < NOUT; c += blockDim.x) {
        float acc[R];
#pragma unroll
        for (int r = 0; r < R; ++r) acc[r] = 0.f;
#pragma unroll 4
        for (int k = 0; k < K; ++k) {
            float w = W[(size_t)k * NOUT + c];
#pragma unroll
            for (int r = 0; r < R; ++r) acc[r] += xs[r][k] * w;
        }
#pragma unroll
        for (int r = 0; r < R; ++r) {
            int n = n0 + r;
            if (n < N) Y[(size_t)n * NOUT + c] = acc[r];
        }
    }
}

// ---------- attention scores: s_src[n,h] = sum_c h[n,h,c]*a_src[h,c] ----------
template<int H, int C>
__global__ void score_k(const float* __restrict__ h, const float* __restrict__ a_src,
                        const float* __restrict__ a_dst,
                        float* __restrict__ s_src, float* __restrict__ s_dst, int N) {
    int idx = blockIdx.x * blockDim.x + threadIdx.x;
    if (idx >= N * H) return;
    int n = idx / H, hh = idx % H;
    const float* hp = h + (size_t)n * H * C + (size_t)hh * C;
    const float* as = a_src + hh * C;
    const float* ad = a_dst + hh * C;
    float ss = 0.f, sd = 0.f;
#pragma unroll 4
    for (int c = 0; c < C; ++c) { float v = hp[c]; ss += v * as[c]; sd += v * ad[c]; }
    s_src[idx] = ss;
    s_dst[idx] = sd;
}

// ---------- edge pass 1: e = leaky_relu(s_src[s]+s_dst[d]); segment max ----------
template<int H>
__global__ void edge_max_k(const int* __restrict__ src, const int* __restrict__ dst, int E, int N,
                           const float* __restrict__ ssrc, const float* __restrict__ sdst,
                           float* __restrict__ ew, unsigned* __restrict__ m) {
    int e = blockIdx.x * blockDim.x + threadIdx.x;
    if (e >= E + N) return;
    int s, d;
    if (e < E) { s = src[e]; d = dst[e]; } else { s = d = e - E; }
#pragma unroll
    for (int h = 0; h < H; ++h) {
        float v = ssrc[s * H + h] + sdst[d * H + h];
        v = v > 0.f ? v : 0.2f * v;
        ew[(size_t)e * H + h] = v;
        atomicMax(&m[d * H + h], encf(v));
    }
}

// ---------- edge pass 2: w = exp(e - m[dst]); segment sum ----------
template<int H>
__global__ void edge_expsum_k(const int* __restrict__ dst, int E, int N,
                              const unsigned* __restrict__ m, float* __restrict__ ew,
                              float* __restrict__ den) {
    int e = blockIdx.x * blockDim.x + threadIdx.x;
    if (e >= E + N) return;
    int d = (e < E) ? dst[e] : (e - E);
#pragma unroll
    for (int h = 0; h < H; ++h) {
        float w = expf(ew[(size_t)e * H + h] - decf(m[d * H + h]));
        ew[(size_t)e * H + h] = w;
        atomicAdd(&den[d * H + h], w);
    }
}

// ---------- edge pass 3: alpha = w / denom[dst] ----------
template<int H>
__global__ void edge_alpha_k(const int* __restrict__ dst, int E, int N,
                             const float* __restrict__ den, float* __restrict__ ew) {
    int e = blockIdx.x * blockDim.x + threadIdx.x;
    if (e >= E + N) return;
    int d = (e < E) ? dst[e] : (e - E);
#pragma unroll
    for (int h = 0; h < H; ++h)
        ew[(size_t)e * H + h] /= den[d * H + h];
}

// ---------- edge pass 4: agg[d,:] += alpha[e,h] * h[s,:] ----------
template<int H, int C>
__global__ void edge_agg_k(const int* __restrict__ src, const int* __restrict__ dst, int E, int N,
                           const float* __restrict__ ew, const float* __restrict__ hin,
                           float* __restrict__ agg) {
    const int HC = H * C;
    size_t idx = (size_t)blockIdx.x * blockDim.x + threadIdx.x;
    size_t total = (size_t)(E + N) * HC;
    if (idx >= total) return;
    int e = (int)(idx / HC);
    int j = (int)(idx % HC);
    int s, d;
    if (e < E) { s = src[e]; d = dst[e]; } else { s = d = e - E; }
    float alpha = ew[(size_t)e * H + (j / C)];
    atomicAdd(&agg[(size_t)d * HC + j], alpha * hin[(size_t)s * HC + j]);
}

// ---------- epilogues ----------
__global__ void bias_elu_k(float* __restrict__ y, const float* __restrict__ b, size_t total, int F) {
    size_t idx = (size_t)blockIdx.x * blockDim.x + threadIdx.x;
    if (idx >= total) return;
    int j = (int)(idx % F);
    float v = y[idx] + b[j];
    y[idx] = v > 0.f ? v : (expf(v) - 1.f);
}
__global__ void bias_add_k(float* __restrict__ y, const float* __restrict__ b, size_t total, int F) {
    size_t idx = (size_t)blockIdx.x * blockDim.x + threadIdx.x;
    if (idx >= total) return;
    int j = (int)(idx % F);
    y[idx] += b[j];
}

// ---------- launch ----------
extern "C" void kernel_launch(void* const* d_in, const int* in_sizes, int n_in,
                              void* d_out, int out_size, void* d_ws, size_t ws_size,
                              hipStream_t stream) {
    const float* x   = (const float*)d_in[0];
    const int*   ei  = (const int*)d_in[1];
    const float* W1  = (const float*)d_in[2];
    const float* as1 = (const float*)d_in[3];
    const float* ad1 = (const float*)d_in[4];
    const float* b1  = (const float*)d_in[5];
    const float* W2  = (const float*)d_in[6];
    const float* as2 = (const float*)d_in[7];
    const float* ad2 = (const float*)d_in[8];
    const float* b2  = (const float*)d_in[9];
    float* out = (float*)d_out;

    const int N  = in_sizes[0] / 128;   // 50000
    const int E  = in_sizes[1] / 2;     // 800000
    const int ET = E + N;               // edges incl. self-loops
    const int* src = ei;
    const int* dst = ei + E;

    // workspace layout (floats)
    float* ws = (float*)d_ws;
    float*    h1    = ws;                              // N*256
    float*    agg1  = h1    + (size_t)N * 256;         // N*256
    float*    ssrc1 = agg1  + (size_t)N * 256;         // N*4
    float*    sdst1 = ssrc1 + (size_t)N * 4;           // N*4
    unsigned* m1    = (unsigned*)(sdst1 + (size_t)N * 4); // N*4
    float*    den1  = (float*)(m1 + (size_t)N * 4);    // N*4
    float*    ssrc2 = den1  + (size_t)N * 4;           // N
    float*    sdst2 = ssrc2 + N;                       // N
    unsigned* m2    = (unsigned*)(sdst2 + N);          // N
    float*    den2  = (float*)(m2 + N);                // N
    float*    ew    = den2 + N;                        // ET*4 (layer1), reused as ET*1 (layer2)
    float*    h2    = h1;                              // reuse h1 buffer for layer-2 features [N,128]

    const int B = 256;
    auto blocks = [](size_t n, int b) { return (int)((n + b - 1) / b); };

    // ---- init ----
    fill_f32_k<<<blocks((size_t)N * 256, B), B, 0, stream>>>(agg1, (size_t)N * 256, 0.f);
    fill_u32_k<<<blocks((size_t)N * 4, B), B, 0, stream>>>(m1, (size_t)N * 4, ENC_NEG_INF);
    fill_f32_k<<<blocks((size_t)N * 4, B), B, 0, stream>>>(den1, (size_t)N * 4, 0.f);
    fill_u32_k<<<blocks((size_t)N, B), B, 0, stream>>>(m2, (size_t)N, ENC_NEG_INF);
    fill_f32_k<<<blocks((size_t)N, B), B, 0, stream>>>(den2, (size_t)N, 0.f);
    fill_f32_k<<<blocks((size_t)out_size, B), B, 0, stream>>>(out, (size_t)out_size, 0.f);

    // ---- layer 1 ----
    gemm_rows_k<128, 256, 8><<<(N + 7) / 8, 256, 0, stream>>>(x, W1, h1, N);
    score_k<4, 64><<<blocks((size_t)N * 4, B), B, 0, stream>>>(h1, as1, ad1, ssrc1, sdst1, N);
    edge_max_k<4><<<blocks((size_t)ET, B), B, 0, stream>>>(src, dst, E, N, ssrc1, sdst1, ew, m1);
    edge_expsum_k<4><<<blocks((size_t)ET, B), B, 0, stream>>>(dst, E, N, m1, ew, den1);
    edge_alpha_k<4><<<blocks((size_t)ET, B), B, 0, stream>>>(dst, E, N, den1, ew);
    edge_agg_k<4, 64><<<blocks((size_t)ET * 256, B), B, 0, stream>>>(src, dst, E, N, ew, h1, agg1);
    bias_elu_k<<<blocks((size_t)N * 256, B), B, 0, stream>>>(agg1, b1, (size_t)N * 256, 256);

    // ---- layer 2 ----
    gemm_rows_k<256, 128, 8><<<(N + 7) / 8, 128, 0, stream>>>(agg1, W2, h2, N);
    score_k<1, 128><<<blocks((size_t)N, B), B, 0, stream>>>(h2, as2, ad2, ssrc2, sdst2, N);
    edge_max_k<1><<<blocks((size_t)ET, B), B, 0, stream>>>(src, dst, E, N, ssrc2, sdst2, ew, m2);
    edge_expsum_k<1><<<blocks((size_t)ET, B), B, 0, stream>>>(dst, E, N, m2, ew, den2);
    edge_alpha_k<1><<<blocks((size_t)ET, B), B, 0, stream>>>(dst, E, N, den2, ew);
    edge_agg_k<1, 128><<<blocks((size_t)ET * 128, B), B, 0, stream>>>(src, dst, E, N, ew, h2, out);
    bias_add_k<<<blocks((size_t)out_size, B), B, 0, stream>>>(out, b2, (size_t)out_size, 128);
}

// Round 2
// 525.119 us; speedup vs baseline: 3.2539x; 3.2539x over previous
//
#include <hip/hip_runtime.h>
#include <cmath>

// ---------- fills ----------
__global__ void fill_i32_k(int* __restrict__ p, size_t n, int v) {
    size_t i = (size_t)blockIdx.x * blockDim.x + threadIdx.x;
    if (i < n) p[i] = v;
}

// ---------- CSR build ----------
__global__ void count_k(const int* __restrict__ dst, int E, int* __restrict__ deg) {
    int e = blockIdx.x * blockDim.x + threadIdx.x;
    if (e < E) atomicAdd(&deg[dst[e]], 1);
}

#define SCAN_BLK 256
#define SCAN_ELEMS 2048   // 8 per thread

__global__ void scan1_k(const int* __restrict__ deg, int* __restrict__ rowstart,
                        int* __restrict__ bsums, int N) {
    __shared__ int sh[SCAN_BLK];
    int t = threadIdx.x;
    int base = blockIdx.x * SCAN_ELEMS + t * 8;
    int vals[8];
    int sum = 0;
#pragma unroll
    for (int i = 0; i < 8; ++i) {
        int idx = base + i;
        vals[i] = (idx < N) ? deg[idx] : 0;
        sum += vals[i];
    }
    sh[t] = sum;
    __syncthreads();
    for (int off = 1; off < SCAN_BLK; off <<= 1) {
        int v = (t >= off) ? sh[t - off] : 0;
        __syncthreads();
        sh[t] += v;
        __syncthreads();
    }
    int run = sh[t] - sum;   // exclusive prefix of this thread within block
    if (t == SCAN_BLK - 1) bsums[blockIdx.x] = sh[t];
#pragma unroll
    for (int i = 0; i < 8; ++i) {
        int idx = base + i;
        if (idx < N) rowstart[idx] = run;
        run += vals[i];
    }
}

__global__ void scan2_k(int* __restrict__ bsums, int nb) {
    if (threadIdx.x == 0 && blockIdx.x == 0) {
        int run = 0;
        for (int i = 0; i < nb; ++i) { int t = bsums[i]; bsums[i] = run; run += t; }
    }
}

__global__ void scan3_k(int* __restrict__ rowstart, const int* __restrict__ bsums, int N, int total) {
    int i = blockIdx.x * blockDim.x + threadIdx.x;
    if (i < N) rowstart[i] += bsums[i / SCAN_ELEMS];
    else if (i == N) rowstart[N] = total;
}

__global__ void initadj_k(const int* __restrict__ rowstart, int* __restrict__ adj,
                          int* __restrict__ cursor, int N) {
    int n = blockIdx.x * blockDim.x + threadIdx.x;
    if (n >= N) return;
    int r = rowstart[n];
    adj[r] = n;          // self-loop first
    cursor[n] = r + 1;
}

__global__ void scatter_k(const int* __restrict__ src, const int* __restrict__ dst, int E,
                          int* __restrict__ cursor, int* __restrict__ adj) {
    int e = blockIdx.x * blockDim.x + threadIdx.x;
    if (e >= E) return;
    int pos = atomicAdd(&cursor[dst[e]], 1);
    adj[pos] = src[e];
}

// ---------- GEMM: Y[N,NOUT] = X[N,K] @ W[K,NOUT], R rows per block ----------
template<int K, int NOUT, int R>
__global__ void gemm_rows_k(const float* __restrict__ X, const float* __restrict__ W,
                            float* __restrict__ Y, int N) {
    __shared__ float xs[R][K];
    int n0 = blockIdx.x * R;
    for (int i = threadIdx.x; i < R * K; i += blockDim.x) {
        int r = i / K, k = i % K;
        int n = n0 + r;
        xs[r][k] = (n < N) ? X[(size_t)n * K + k] : 0.f;
    }
    __syncthreads();
    for (int c = threadIdx.x; c < NOUT; c += blockDim.x) {
        float acc[R];
#pragma unroll
        for (int r = 0; r < R; ++r) acc[r] = 0.f;
#pragma unroll 4
        for (int k = 0; k < K; ++k) {
            float w = W[(size_t)k * NOUT + c];
#pragma unroll
            for (int r = 0; r < R; ++r) acc[r] += xs[r][k] * w;
        }
#pragma unroll
        for (int r = 0; r < R; ++r) {
            int n = n0 + r;
            if (n < N) Y[(size_t)n * NOUT + c] = acc[r];
        }
    }
}

// ---------- attention scores ----------
template<int H, int C>
__global__ void score_k(const float* __restrict__ h, const float* __restrict__ a_src,
                        const float* __restrict__ a_dst,
                        float* __restrict__ s_src, float* __restrict__ s_dst, int N) {
    int idx = blockIdx.x * blockDim.x + threadIdx.x;
    if (idx >= N * H) return;
    int n = idx / H, hh = idx % H;
    const float* hp = h + (size_t)n * H * C + (size_t)hh * C;
    const float* as = a_src + hh * C;
    const float* ad = a_dst + hh * C;
    float ss = 0.f, sd = 0.f;
#pragma unroll 4
    for (int c = 0; c < C; ++c) { float v = hp[c]; ss += v * as[c]; sd += v * ad[c]; }
    s_src[idx] = ss;
    s_dst[idx] = sd;
}

// ---------- fused per-node softmax + gather-aggregate + bias(+ELU) ----------
// one 64-lane wave per destination node; 4 waves per block
template<int H, int C, bool ELU>
__global__ void node_agg_k(const int* __restrict__ rowstart, const int* __restrict__ adj,
                           const float* __restrict__ ssrc, const float* __restrict__ sdst,
                           const float* __restrict__ hin, const float* __restrict__ bias,
                           float* __restrict__ out, int N) {
    constexpr int HC = H * C;
    constexpr int FPL = HC / 64;            // features per lane (4 or 2)
    int lane = threadIdx.x & 63;
    int n = blockIdx.x * (blockDim.x >> 6) + (threadIdx.x >> 6);
    if (n >= N) return;
    int r0 = rowstart[n], r1 = rowstart[n + 1];

    float sd[H], m[H], l[H];
#pragma unroll
    for (int h = 0; h < H; ++h) { sd[h] = sdst[n * H + h]; m[h] = -1e30f; l[h] = 0.f; }

    // pass 1: online softmax stats, lanes strided over edges
    for (int e = r0 + lane; e < r1; e += 64) {
        int s = adj[e];
#pragma unroll
        for (int h = 0; h < H; ++h) {
            float v = ssrc[s * H + h] + sd[h];
            v = v > 0.f ? v : 0.2f * v;
            float mn = fmaxf(m[h], v);
            l[h] = l[h] * __expf(m[h] - mn) + __expf(v - mn);
            m[h] = mn;
        }
    }
    // wave-wide combine of (m, l)
#pragma unroll
    for (int off = 32; off; off >>= 1) {
#pragma unroll
        for (int h = 0; h < H; ++h) {
            float mo = __shfl_xor(m[h], off, 64);
            float lo = __shfl_xor(l[h], off, 64);
            float mn = fmaxf(m[h], mo);
            l[h] = l[h] * __expf(m[h] - mn) + lo * __expf(mo - mn);
            m[h] = mn;
        }
    }

    // pass 2: gather-weighted aggregation
    int hA = (lane * FPL) / C;
    float mh = m[hA], invl = 1.f / l[hA], sdh = sd[hA];
    float acc[FPL];
#pragma unroll
    for (int f = 0; f < FPL; ++f) acc[f] = 0.f;

    for (int e = r0; e < r1; ++e) {
        int s = adj[e];
        float v = ssrc[s * H + hA] + sdh;
        v = v > 0.f ? v : 0.2f * v;
        float alpha = __expf(v - mh) * invl;
        const float* hp = hin + (size_t)s * HC + lane * FPL;
        if constexpr (FPL == 4) {
            float4 x = *reinterpret_cast<const float4*>(hp);
            acc[0] += alpha * x.x; acc[1] += alpha * x.y;
            acc[2] += alpha * x.z; acc[3] += alpha * x.w;
        } else {
            float2 x = *reinterpret_cast<const float2*>(hp);
            acc[0] += alpha * x.x; acc[1] += alpha * x.y;
        }
    }

    float* op = out + (size_t)n * HC + lane * FPL;
#pragma unroll
    for (int f = 0; f < FPL; ++f) {
        float v = acc[f] + bias[lane * FPL + f];
        if (ELU) v = v > 0.f ? v : (__expf(v) - 1.f);
        op[f] = v;
    }
}

// ---------- launch ----------
extern "C" void kernel_launch(void* const* d_in, const int* in_sizes, int n_in,
                              void* d_out, int out_size, void* d_ws, size_t ws_size,
                              hipStream_t stream) {
    const float* x   = (const float*)d_in[0];
    const int*   ei  = (const int*)d_in[1];
    const float* W1  = (const float*)d_in[2];
    const float* as1 = (const float*)d_in[3];
    const float* ad1 = (const float*)d_in[4];
    const float* b1  = (const float*)d_in[5];
    const float* W2  = (const float*)d_in[6];
    const float* as2 = (const float*)d_in[7];
    const float* ad2 = (const float*)d_in[8];
    const float* b2  = (const float*)d_in[9];
    float* out = (float*)d_out;

    const int N  = in_sizes[0] / 128;   // 50000
    const int E  = in_sizes[1] / 2;     // 800000
    const int ET = E + N;
    const int* src = ei;
    const int* dst = ei + E;

    // workspace layout
    float* ws = (float*)d_ws;
    float* h1    = ws;                               // N*256
    float* agg1  = h1    + (size_t)N * 256;          // N*256
    float* ssrc1 = agg1  + (size_t)N * 256;          // N*4
    float* sdst1 = ssrc1 + (size_t)N * 4;            // N*4
    float* ssrc2 = sdst1 + (size_t)N * 4;            // N
    float* sdst2 = ssrc2 + N;                        // N
    int*   deg   = (int*)(sdst2 + N);                // N   (reused as cursor)
    int*   rowst = deg + N;                          // N+1
    int*   bsums = rowst + N + 1;                    // 64
    int*   adj   = bsums + 64;                       // ET
    float* h2    = h1;                               // reuse for layer-2 features [N,128]

    const int B = 256;
    auto blocks = [](size_t n, int b) { return (int)((n + b - 1) / b); };
    const int nscan = (N + SCAN_ELEMS - 1) / SCAN_ELEMS;

    // ---- CSR build (shared by both layers) ----
    fill_i32_k<<<blocks(N, B), B, 0, stream>>>(deg, N, 1);          // self-loop
    count_k<<<blocks(E, B), B, 0, stream>>>(dst, E, deg);
    scan1_k<<<nscan, SCAN_BLK, 0, stream>>>(deg, rowst, bsums, N);
    scan2_k<<<1, 64, 0, stream>>>(bsums, nscan);
    scan3_k<<<blocks(N + 1, B), B, 0, stream>>>(rowst, bsums, N, ET);
    initadj_k<<<blocks(N, B), B, 0, stream>>>(rowst, adj, deg, N);  // deg becomes cursor
    scatter_k<<<blocks(E, B), B, 0, stream>>>(src, dst, E, deg, adj);

    // ---- layer 1 ----
    gemm_rows_k<128, 256, 16><<<(N + 15) / 16, 256, 0, stream>>>(x, W1, h1, N);
    score_k<4, 64><<<blocks((size_t)N * 4, B), B, 0, stream>>>(h1, as1, ad1, ssrc1, sdst1, N);
    node_agg_k<4, 64, true><<<(N + 3) / 4, 256, 0, stream>>>(rowst, adj, ssrc1, sdst1, h1, b1, agg1, N);

    // ---- layer 2 ----
    gemm_rows_k<256, 128, 16><<<(N + 15) / 16, 128, 0, stream>>>(agg1, W2, h2, N);
    score_k<1, 128><<<blocks(N, B), B, 0, stream>>>(h2, as2, ad2, ssrc2, sdst2, N);
    node_agg_k<1, 128, false><<<(N + 3) / 4, 256, 0, stream>>>(rowst, adj, ssrc2, sdst2, h2, b2, out, N);
}